// Round 1
// baseline (20.041 us; speedup 1.0000x reference)
//
#include <hip/hip_runtime.h>
#include <hip/hip_bf16.h>

#define MQ 32
#define NG 256
#define DD 128

// all-lanes butterfly reduction over the 64-lane wave
__device__ __forceinline__ float wred(float v) {
    #pragma unroll
    for (int o = 32; o > 0; o >>= 1) v += __shfl_xor(v, o);
    return v;
}

__global__ __launch_bounds__(256, 2)
void InferenceXtt_kernel(const float* __restrict__ qf,
                         const float* __restrict__ x,
                         const float* __restrict__ Mp,
                         const float* __restrict__ zep,
                         float* __restrict__ out) {
    __shared__ float Mp_sh[DD * DD];           // 64 KB
    __shared__ float u_sh[4][4][DD];           // 8 KB: [wave][jj][d]

    const int t = threadIdx.x;
    const int w = t >> 6;       // wave 0..3
    const int l = t & 63;       // lane
    const int bid = blockIdx.x;
    const int i  = bid >> 4;              // query index 0..31
    const int j0 = (bid & 15) * 16 + w * 4;  // this wave's first gallery idx

    // ---- stage Mp into LDS (coalesced float4) ----
    {
        const float4* g = (const float4*)Mp;
        float4* s = (float4*)Mp_sh;
        #pragma unroll
        for (int r = 0; r < 16; ++r) s[t + r * 256] = g[t + r * 256];
    }

    const float ze = zep[0];

    // ---- per-pair u/v, dist0, stash u in LDS ----
    const float q0 = qf[i * DD + l];
    const float q1 = qf[i * DD + l + 64];

    float ub0[4], ub1[4], dist0[4];
    #pragma unroll
    for (int jj = 0; jj < 4; ++jj) {
        const int j = j0 + jj;
        const float x0 = x[j * DD + l];
        const float x1 = x[j * DD + l + 64];
        const float u0 = fmaxf(q0, x0), u1 = fmaxf(q1, x1);
        const float v0 = fminf(q0, x0), v1 = fminf(q1, x1);
        ub0[jj] = u0; ub1[jj] = u1;
        u_sh[w][jj][l]      = u0;
        u_sh[w][jj][l + 64] = u1;
        const float su = wred(u0 + u1);
        const float sv = wred(v0 + v1);
        dist0[jj] = sv / su;
    }
    __syncthreads();   // Mp_sh ready for all waves

    // ---- penalty: sum_{a,b} max(ze, u[a]*u[b] - Mp[a,b]) ----
    float acc[4] = {0.f, 0.f, 0.f, 0.f};
    #pragma unroll 4
    for (int a = 0; a < DD; ++a) {
        const float mp0 = Mp_sh[a * DD + l];        // bank l%32: conflict-free
        const float mp1 = Mp_sh[a * DD + l + 64];
        #pragma unroll
        for (int jj = 0; jj < 4; ++jj) {
            const float ua = u_sh[w][jj][a];        // broadcast: free
            acc[jj] += fmaxf(ze, fmaf(ua, ub0[jj], -mp0));
            acc[jj] += fmaxf(ze, fmaf(ua, ub1[jj], -mp1));
        }
    }

    // ---- reduce + write ----
    #pragma unroll
    for (int jj = 0; jj < 4; ++jj) {
        const float pen = wred(acc[jj]);
        if (l == jj) out[i * NG + (j0 + jj)] = dist0[jj] - 0.001f * pen;
    }
}

extern "C" void kernel_launch(void* const* d_in, const int* in_sizes, int n_in,
                              void* d_out, int out_size, void* d_ws, size_t ws_size,
                              hipStream_t stream) {
    const float* qf = (const float*)d_in[0];
    const float* x  = (const float*)d_in[1];
    const float* Mp = (const float*)d_in[2];
    const float* ze = (const float*)d_in[3];
    float* out = (float*)d_out;
    InferenceXtt_kernel<<<dim3(MQ * 16), dim3(256), 0, stream>>>(qf, x, Mp, ze, out);
}

// Round 2
// 19.750 us; speedup vs baseline: 1.0147x; 1.0147x over previous
//
#include <hip/hip_runtime.h>
#include <hip/hip_bf16.h>

#define MQ 32
#define NG 256
#define DD 128
#define PAD 20   // u_T row stride (floats); keeps float4 alignment, breaks pow2 banks

// all-lanes butterfly reduction over the 64-lane wave
__device__ __forceinline__ float wred(float v) {
    #pragma unroll
    for (int o = 32; o > 0; o >>= 1) v += __shfl_xor(v, o);
    return v;
}

__global__ __launch_bounds__(256, 2)
void InferenceXtt_kernel(const float* __restrict__ qf,
                         const float* __restrict__ x,
                         const float* __restrict__ Mp,
                         const float* __restrict__ zep,
                         float* __restrict__ out) {
    __shared__ float Mp_sh[DD * DD];      // 64 KB, holds Mp + ze
    __shared__ float u_T[DD * PAD];       // 10 KB, u transposed: u_T[d*PAD + pair]
    __shared__ float dist0_sh[16], su_sh[16], msum_sh[4], pen_sh[2][16];

    const int t = threadIdx.x;
    const int w = t >> 6;       // wave 0..3
    const int l = t & 63;       // lane
    const int i  = blockIdx.x >> 4;          // query index
    const int j0 = (blockIdx.x & 15) * 16;   // block's first gallery idx

    const float ze = zep[0];

    // ---- stage Mp + ze into LDS, accumulate sum(Mp+ze) ----
    {
        const float4* g = (const float4*)Mp;
        float4* s = (float4*)Mp_sh;
        float4 ms4 = make_float4(0.f, 0.f, 0.f, 0.f);
        #pragma unroll
        for (int r = 0; r < 16; ++r) {
            float4 v = g[t + r * 256];
            v.x += ze; v.y += ze; v.z += ze; v.w += ze;
            s[t + r * 256] = v;
            ms4.x += v.x; ms4.y += v.y; ms4.z += v.z; ms4.w += v.w;
        }
        float ms = wred((ms4.x + ms4.y) + (ms4.z + ms4.w));
        if (l == 0) msum_sh[w] = ms;
    }

    // ---- u-prep: wave w computes u for pairs w*4..w*4+3, dist0, su ----
    {
        const float q0 = qf[i * DD + l];
        const float q1 = qf[i * DD + l + 64];
        #pragma unroll
        for (int pp = 0; pp < 4; ++pp) {
            const int p = w * 4 + pp;
            const int j = j0 + p;
            const float x0 = x[j * DD + l];
            const float x1 = x[j * DD + l + 64];
            const float u0 = fmaxf(q0, x0), u1 = fmaxf(q1, x1);
            const float v0 = fminf(q0, x0), v1 = fminf(q1, x1);
            u_T[l * PAD + p]        = u0;
            u_T[(l + 64) * PAD + p] = u1;
            const float su = wred(u0 + u1);
            const float sv = wred(v0 + v1);
            if (l == 0) { su_sh[p] = su; dist0_sh[p] = sv / su; }
        }
    }

    // ---- ub register tile from GLOBAL (L2-resident): lane owns 4 b-cols ----
    const int half = l >> 5;            // which of the 2 rows per step
    const int b4   = (l & 31) * 4;      // this lane's 4 b-columns
    const int g8   = w & 1;             // pair-group: pairs g8*8 .. g8*8+7
    const int h    = w >> 1;            // row-half: rows h*64 .. h*64+63
    const int jg   = g8 * 8;

    float ub[8][4];
    {
        const float4 qv = *(const float4*)&qf[i * DD + b4];
        #pragma unroll
        for (int jj = 0; jj < 8; ++jj) {
            const float4 xv = *(const float4*)&x[(j0 + jg + jj) * DD + b4];
            ub[jj][0] = fmaxf(qv.x, xv.x);
            ub[jj][1] = fmaxf(qv.y, xv.y);
            ub[jj][2] = fmaxf(qv.z, xv.z);
            ub[jj][3] = fmaxf(qv.w, xv.w);
        }
    }

    __syncthreads();   // Mp_sh + u_T ready

    // ---- penalty core: S = sum |u_a*u_b - Mze| over this wave's rows/pairs ----
    // per step: 2 rows (one per half-wave), 4 b's (registers), 8 pairs
    float acc[8] = {0.f,0.f,0.f,0.f,0.f,0.f,0.f,0.f};
    const float* mprow = &Mp_sh[(h * 64 + half) * DD + b4];
    const float* uarow = &u_T[(h * 64 + half) * PAD + jg];
    #pragma unroll 4
    for (int s = 0; s < 32; ++s) {
        const float4 mp  = *(const float4*)mprow;        // ds_read_b128, contiguous
        const float4 ua0 = *(const float4*)uarow;        // broadcast (2 addrs/wave)
        const float4 ua1 = *(const float4*)(uarow + 4);
        mprow += 2 * DD;
        uarow += 2 * PAD;
        const float ua[8] = {ua0.x, ua0.y, ua0.z, ua0.w, ua1.x, ua1.y, ua1.z, ua1.w};
        #pragma unroll
        for (int jj = 0; jj < 8; ++jj) {
            acc[jj] += __builtin_fabsf(fmaf(ua[jj], ub[jj][0], -mp.x));
            acc[jj] += __builtin_fabsf(fmaf(ua[jj], ub[jj][1], -mp.y));
            acc[jj] += __builtin_fabsf(fmaf(ua[jj], ub[jj][2], -mp.z));
            acc[jj] += __builtin_fabsf(fmaf(ua[jj], ub[jj][3], -mp.w));
        }
    }

    // ---- reduce partial |.| sums, combine halves ----
    #pragma unroll
    for (int jj = 0; jj < 8; ++jj) {
        const float S = wred(acc[jj]);
        if (l == 0) pen_sh[h][jg + jj] = S;
    }
    __syncthreads();

    if (t < 16) {
        const float S  = pen_sh[0][t] + pen_sh[1][t];
        const float su = su_sh[t];
        const float sumMze = (msum_sh[0] + msum_sh[1]) + (msum_sh[2] + msum_sh[3]);
        const float pen = 16384.f * ze + 0.5f * (su * su - sumMze + S);
        out[i * NG + j0 + t] = dist0_sh[t] - 0.001f * pen;
    }
}

extern "C" void kernel_launch(void* const* d_in, const int* in_sizes, int n_in,
                              void* d_out, int out_size, void* d_ws, size_t ws_size,
                              hipStream_t stream) {
    const float* qf = (const float*)d_in[0];
    const float* x  = (const float*)d_in[1];
    const float* Mp = (const float*)d_in[2];
    const float* ze = (const float*)d_in[3];
    float* out = (float*)d_out;
    InferenceXtt_kernel<<<dim3(MQ * 16), dim3(256), 0, stream>>>(qf, x, Mp, ze, out);
}

// Round 3
// 19.339 us; speedup vs baseline: 1.0363x; 1.0212x over previous
//
#include <hip/hip_runtime.h>
#include <hip/hip_bf16.h>

#define MQ 32
#define NG 256
#define DD 128

// full-wave butterfly reduction (64 lanes)
__device__ __forceinline__ float wred64(float v) {
    #pragma unroll
    for (int o = 32; o > 0; o >>= 1) v += __shfl_xor(v, o);
    return v;
}
// half-wave reduction (32 lanes; xor offsets < 32 stay within the half)
__device__ __forceinline__ float hred32(float v) {
    #pragma unroll
    for (int o = 16; o > 0; o >>= 1) v += __shfl_xor(v, o);
    return v;
}

__global__ __launch_bounds__(256, 4)
void InferenceXtt_kernel(const float* __restrict__ qf,
                         const float* __restrict__ x,
                         const float* __restrict__ Mp,
                         const float* __restrict__ zep,
                         float* __restrict__ out) {
    __shared__ float u_T[DD * 12];          // 6 KB, u transposed: u_T[d*12 + p]
    __shared__ float su_sh[8], dist0_sh[8];
    __shared__ float pen_sh[4][8];
    __shared__ float msum_sh[4];

    const int t = threadIdx.x;
    const int w = t >> 6;                 // wave 0..3
    const int l = t & 63;                 // lane
    const int k = l & 31;                 // lane within half-wave
    const int d0 = k * 4;                 // this lane's 4 columns
    const int i  = blockIdx.x >> 5;       // query index 0..31
    const int j0 = (blockIdx.x & 31) * 8; // block's first gallery idx (8 pairs)

    const float ze = zep[0];

    // ---- u-prep: half-wave group (t>>5) owns pair p; writes u_T, su, dist0 ----
    {
        const int p = t >> 5;             // 0..7
        const float4 qv = *(const float4*)&qf[i * DD + d0];
        const float4 xv = *(const float4*)&x[(j0 + p) * DD + d0];
        const float ux = fmaxf(qv.x, xv.x), uy = fmaxf(qv.y, xv.y);
        const float uz = fmaxf(qv.z, xv.z), uw = fmaxf(qv.w, xv.w);
        const float vx = fminf(qv.x, xv.x), vy = fminf(qv.y, xv.y);
        const float vz = fminf(qv.z, xv.z), vw = fminf(qv.w, xv.w);
        u_T[(d0 + 0) * 12 + p] = ux;
        u_T[(d0 + 1) * 12 + p] = uy;
        u_T[(d0 + 2) * 12 + p] = uz;
        u_T[(d0 + 3) * 12 + p] = uw;
        const float su = hred32((ux + uy) + (uz + uw));
        const float sv = hred32((vx + vy) + (vz + vw));
        if (k == 0) { su_sh[p] = su; dist0_sh[p] = sv / su; }
    }

    // ---- ub register tile: this lane's 4 cols for all 8 pairs (L2-resident) ----
    float ub[8][4];
    {
        const float4 qv = *(const float4*)&qf[i * DD + d0];
        #pragma unroll
        for (int p = 0; p < 8; ++p) {
            const float4 xv = *(const float4*)&x[(j0 + p) * DD + d0];
            ub[p][0] = fmaxf(qv.x, xv.x);
            ub[p][1] = fmaxf(qv.y, xv.y);
            ub[p][2] = fmaxf(qv.z, xv.z);
            ub[p][3] = fmaxf(qv.w, xv.w);
        }
    }

    __syncthreads();   // u_T ready

    // ---- core: wave w owns rows w*32..w*32+31; Mp streamed from L2 ----
    float acc[8] = {0.f,0.f,0.f,0.f,0.f,0.f,0.f,0.f};
    float msum = 0.f;
    const int half = l >> 5;              // 2 rows per step, one per half-wave
    const float* mp_g = &Mp[(w * 32 + half) * DD + d0];
    const float* ua_g = &u_T[(w * 32 + half) * 12];
    #pragma unroll 2
    for (int s = 0; s < 16; ++s) {
        const float4 mp  = *(const float4*)mp_g;      // global_load_dwordx4, L2 hit
        const float4 ua0 = *(const float4*)ua_g;      // LDS broadcast
        const float4 ua1 = *(const float4*)(ua_g + 4);
        mp_g += 2 * DD;
        ua_g += 2 * 12;
        msum += (mp.x + mp.y) + (mp.z + mp.w);
        const float m0 = mp.x + ze, m1 = mp.y + ze;
        const float m2 = mp.z + ze, m3 = mp.w + ze;
        const float ua[8] = {ua0.x, ua0.y, ua0.z, ua0.w, ua1.x, ua1.y, ua1.z, ua1.w};
        #pragma unroll
        for (int p = 0; p < 8; ++p) {
            acc[p] += __builtin_fabsf(fmaf(ua[p], ub[p][0], -m0));
            acc[p] += __builtin_fabsf(fmaf(ua[p], ub[p][1], -m1));
            acc[p] += __builtin_fabsf(fmaf(ua[p], ub[p][2], -m2));
            acc[p] += __builtin_fabsf(fmaf(ua[p], ub[p][3], -m3));
        }
    }

    // ---- reductions ----
    #pragma unroll
    for (int p = 0; p < 8; ++p) {
        const float S = wred64(acc[p]);
        if (l == p) pen_sh[w][p] = S;
    }
    const float ms = wred64(msum);
    if (l == 0) msum_sh[w] = ms;
    __syncthreads();

    if (t < 8) {
        const float S = (pen_sh[0][t] + pen_sh[1][t]) + (pen_sh[2][t] + pen_sh[3][t]);
        const float sumMp = (msum_sh[0] + msum_sh[1]) + (msum_sh[2] + msum_sh[3]);
        const float su = su_sh[t];
        // pen = 16384*ze + 0.5*(su^2 - (sumMp + 16384*ze) + S) = 8192*ze + 0.5*(su^2 - sumMp + S)
        const float pen = 8192.f * ze + 0.5f * (fmaf(su, su, -sumMp) + S);
        out[i * NG + j0 + t] = dist0_sh[t] - 0.001f * pen;
    }
}

extern "C" void kernel_launch(void* const* d_in, const int* in_sizes, int n_in,
                              void* d_out, int out_size, void* d_ws, size_t ws_size,
                              hipStream_t stream) {
    const float* qf = (const float*)d_in[0];
    const float* x  = (const float*)d_in[1];
    const float* Mp = (const float*)d_in[2];
    const float* ze = (const float*)d_in[3];
    float* out = (float*)d_out;
    InferenceXtt_kernel<<<dim3(MQ * 32), dim3(256), 0, stream>>>(qf, x, Mp, ze, out);
}